// Round 11
// baseline (91.201 us; speedup 1.0000x reference)
//
#include <hip/hip_runtime.h>

__device__ __forceinline__ float fexp2(float x) { return __builtin_amdgcn_exp2f(x); }
__device__ __forceinline__ float flog2(float x) { return __builtin_amdgcn_logf(x); }

struct Node { float o0, o1, o2, s0, s1, s2; };

// core symmetric-pair term: wsm*wr*sum(t^0.8) + wl*wsd*sum(t^2)
__device__ __forceinline__ float pair_core(const Node& I, const Node& J,
                                           float wsm, float wl, float wsd)
{
    float d0 = I.o0 - J.o0, d1 = I.o1 - J.o1, d2 = I.o2 - J.o2;
    float sO = fmaf(d0, d0, fmaf(d1, d1, d2 * d2));
    float t0 = fabsf(I.s0 - J.s0) + 1e-8f;
    float t1 = fabsf(I.s1 - J.s1) + 1e-8f;
    float t2 = fabsf(I.s2 - J.s2) + 1e-8f;
    float ps = fexp2(0.8f * flog2(t0)) + fexp2(0.8f * flog2(t1)) + fexp2(0.8f * flog2(t2));
    float wr = fexp2(-0.72134752044448169f * sO);   // exp(-0.5*sO)
    float sq = fmaf(t0, t0, fmaf(t1, t1, t2 * t2));
    return fmaf(wsm * wr, ps, wl * wsd * sq);
}

// interior pixel: all pair multiplicities are 1
__device__ __forceinline__ float pixel_fast(
    const Node& C, const Node& E, const Node& S, const Node& SE, const Node& SW,
    float mi, float mE, float mS, float mSE, float mSW)
{
    float a = fmaf(mi, 3e-16f - 1.1943215e-6f, 1.1943215e-6f);  // center offset
    a += pair_core(C, E,  2.f - mi - mE,  mi + mE,  0.60653065971263342f);
    a += pair_core(C, S,  2.f - mi - mS,  mi + mS,  0.60653065971263342f);
    a += pair_core(C, SE, 2.f - mi - mSE, mi + mSE, 0.36787944117144233f);
    a += pair_core(C, SW, 2.f - mi - mSW, mi + mSW, 0.36787944117144233f);
    return a;
}

// border pixel: reflection multiplicities / zero weights (verified exact R4-R10)
__device__ __forceinline__ float pixel_border(
    const Node& C, const Node& E, const Node& S, const Node& SE, const Node& SW,
    float mi, float mE, float mS, float mSE, float mSW, int h, int w)
{
    float aE = (w == 0)   ? 2.f : 1.f, bE = (w == 510) ? 2.f : 1.f;
    float aS = (h == 0)   ? 2.f : 1.f, bS = (h == 510) ? 2.f : 1.f;
    float aW = (w == 511) ? 2.f : 1.f, bW = (w == 1)   ? 2.f : 1.f;
    bool  vE = (w <= 510), vS = (h <= 510);
    bool  vD = vS && vE,   vW = vS && (w >= 1);
    float cEf = vE ? aE : 0.f,      cEb = vE ? bE : 0.f;
    float cSf = vS ? aS : 0.f,      cSb = vS ? bS : 0.f;
    float cDf = vD ? aS * aE : 0.f, cDb = vD ? bS * bE : 0.f;
    float cWf = vW ? aS * aW : 0.f, cWb = vW ? bS * bW : 0.f;

    float a = fmaf(mi, 3e-16f - 1.1943215e-6f, 1.1943215e-6f);
    a += pair_core(C, E,  fmaf(cEf, -mi, cEf) + fmaf(cEb, -mE,  cEb), fmaf(cEf, mi, cEb * mE),  0.60653065971263342f);
    a += pair_core(C, S,  fmaf(cSf, -mi, cSf) + fmaf(cSb, -mS,  cSb), fmaf(cSf, mi, cSb * mS),  0.60653065971263342f);
    a += pair_core(C, SE, fmaf(cDf, -mi, cDf) + fmaf(cDb, -mSE, cDb), fmaf(cDf, mi, cDb * mSE), 0.36787944117144233f);
    a += pair_core(C, SW, fmaf(cWf, -mi, cWf) + fmaf(cWb, -mSW, cWb), fmaf(cWf, mi, cWb * mSW), 0.36787944117144233f);
    return a;
}

// load one image row: 4-col window (cm1, c, cp1, cp2 pre-reflected) x 6 planes
__device__ __forceinline__ void load_row(float R[6][4], const float* const pb[6],
                                         int row, int cm1, int c, int cp1, int cp2)
{
    const int rb = (row > 511 ? 1022 - row : row) << 9;
    #pragma unroll
    for (int p = 0; p < 6; ++p) {
        const float* g = pb[p] + rb;
        R[p][0] = g[cm1]; R[p][1] = g[c]; R[p][2] = g[cp1]; R[p][3] = g[cp2];
    }
}

// masks of B_'s row at window cols 0..2 (= c-1, c, c+1), using C_ = next row
__device__ __forceinline__ void mask3(float M[3], const float B_[6][4], const float C_[6][4])
{
    #pragma unroll
    for (int j = 0; j < 3; ++j) {
        float eo = 0.f, es = 0.f;
        #pragma unroll
        for (int p = 0; p < 3; ++p) {
            float a = B_[p][j];
            float d1 = a - C_[p][j], d2 = a - B_[p][j + 1];
            eo += d1 * d1 + d2 * d2;
            float s = B_[p + 3][j];
            float f1 = s - C_[p + 3][j], f2 = s - B_[p + 3][j + 1];
            es += f1 * f1 + f2 * f2;
        }
        M[j] = (eo < 1.f && es - eo > 1.f) ? 1.f : 0.f;
    }
}

__device__ __forceinline__ Node mk(const float R[6][4], int i)
{
    Node n; n.o0 = R[0][i]; n.o1 = R[1][i]; n.o2 = R[2][i];
    n.s0 = R[3][i]; n.s1 = R[4][i]; n.s2 = R[5][i]; return n;
}

// one march step: A=row r, B=row r+1; N receives row r+3 (issued first)
#define MSTEP(A_, B_, C_, N_, S_, DOLOAD_)                                        \
    {                                                                             \
        if (DOLOAD_) load_row(N_, pb, h0 + (S_) + 3, cm1, c, cp1, cp2);           \
        float mN[3]; mask3(mN, B_, C_);                                           \
        if (wborder) {                                                            \
            acc += pixel_border(mk(A_,1), mk(A_,2), mk(B_,1), mk(B_,2), mk(B_,0), \
                                mC[1], mC[2], mN[1], mN[2], mN[0], h0 + (S_), c); \
        } else {                                                                  \
            acc += pixel_fast(mk(A_,1), mk(A_,2), mk(B_,1), mk(B_,2), mk(B_,0),   \
                              mC[1], mC[2], mN[1], mN[2], mN[0]);                 \
        }                                                                         \
        mC[0] = mN[0]; mC[1] = mN[1]; mC[2] = mN[2];                              \
    }

__global__ __launch_bounds__(256, 4) void smooth_loss_kernel(
    const float* __restrict__ orig, const float* __restrict__ smo,
    float* __restrict__ out)
{
    const int tid  = threadIdx.x;
    const int bid  = blockIdx.x;        // 8 imgs * 64 bands * 2 col-halves
    const int b    = bid >> 7;
    const int rem  = bid & 127;
    const int band = rem >> 1;
    const int half = rem & 1;
    const int h0   = band << 3;         // 8-row segment
    const int c    = (half << 8) | tid; // own column

    // pre-reflected window col indices (c-1, c, c+1, c+2)
    const int cm1 = (c == 0)   ? 1   : c - 1;
    const int cp1 = (c == 511) ? 510 : c + 1;
    const int cp2 = (c >= 510) ? 1022 - (c + 2) : c + 2;

    const int trow = band;
    const int wc   = (half << 8) | (tid & 192);   // wave's first col
    const bool wborder = (trow == 0) | (trow == 63) | (wc == 0) | (wc == 448);

    const float* pb[6];
    #pragma unroll
    for (int p = 0; p < 3; ++p) {
        pb[p]     = orig + ((b * 3 + p) << 18);
        pb[p + 3] = smo  + ((b * 3 + p) << 18);
    }

    float D0[6][4], D1[6][4], D2[6][4], D3[6][4];
    float mC[3];
    float acc = 0.f;

    load_row(D0, pb, h0,     cm1, c, cp1, cp2);
    load_row(D1, pb, h0 + 1, cm1, c, cp1, cp2);
    load_row(D2, pb, h0 + 2, cm1, c, cp1, cp2);
    mask3(mC, D0, D1);                  // masks of row h0

    MSTEP(D0, D1, D2, D3, 0, 1)
    MSTEP(D1, D2, D3, D0, 1, 1)
    MSTEP(D2, D3, D0, D1, 2, 1)
    MSTEP(D3, D0, D1, D2, 3, 1)
    MSTEP(D0, D1, D2, D3, 4, 1)
    MSTEP(D1, D2, D3, D0, 5, 1)
    MSTEP(D2, D3, D0, D1, 6, 1)
    MSTEP(D3, D0, D1, D2, 7, 0)

    acc *= (1.0f / 56623104.0f);        // mean over 8*9*3*512*512

    #pragma unroll
    for (int o = 32; o > 0; o >>= 1)
        acc += __shfl_down(acc, o, 64);

    __shared__ float wsum[4];
    const int lane = tid & 63;
    const int wid  = tid >> 6;
    if (lane == 0) wsum[wid] = acc;
    __syncthreads();
    if (tid == 0)
        atomicAdd(out, wsum[0] + wsum[1] + wsum[2] + wsum[3]);
}

extern "C" void kernel_launch(void* const* d_in, const int* in_sizes, int n_in,
                              void* d_out, int out_size, void* d_ws, size_t ws_size,
                              hipStream_t stream) {
    const float* orig = (const float*)d_in[0];
    const float* smo  = (const float*)d_in[1];
    float* out = (float*)d_out;

    (void)hipMemsetAsync(out, 0, sizeof(float), stream);
    smooth_loss_kernel<<<1024, 256, 0, stream>>>(orig, smo, out);
}

// Round 12
// 33.725 us; speedup vs baseline: 2.7042x; 2.7042x over previous
//
#include <hip/hip_runtime.h>

__device__ __forceinline__ float fexp2(float x) { return __builtin_amdgcn_exp2f(x); }
__device__ __forceinline__ float flog2(float x) { return __builtin_amdgcn_logf(x); }

#define WS1 0.60653065971263342f   // exp(-0.5)
#define WS2 0.36787944117144233f   // exp(-1)

struct PairP { float ps, sq; };    // ps = wr*sum(t^0.8) ; sq = wsd*sum(t^2)

// mask-independent pair partials between I[.][CI] and J[.][CJ]
template<int CI, int CJ>
__device__ __forceinline__ PairP pp(const float (&I)[6][4], const float (&J)[6][4], float wsd)
{
    float d0 = I[0][CI] - J[0][CJ], d1 = I[1][CI] - J[1][CJ], d2 = I[2][CI] - J[2][CJ];
    float sO = fmaf(d0, d0, fmaf(d1, d1, d2 * d2));
    float t0 = fabsf(I[3][CI] - J[3][CJ]) + 1e-8f;
    float t1 = fabsf(I[4][CI] - J[4][CJ]) + 1e-8f;
    float t2 = fabsf(I[5][CI] - J[5][CJ]) + 1e-8f;
    PairP r;
    r.ps = fexp2(-0.72134752044448169f * sO) *
           (fexp2(0.8f * flog2(t0)) + fexp2(0.8f * flog2(t1)) + fexp2(0.8f * flog2(t2)));
    r.sq = wsd * fmaf(t0, t0, fmaf(t1, t1, t2 * t2));
    return r;
}

// load one image row: 4-col window (cm1, c, cp1, cp2 pre-reflected) x 6 planes
__device__ __forceinline__ void load_row(float R[6][4], const float* const pb[6],
                                         int row, int cm1, int c, int cp1, int cp2)
{
    const int rb = (row > 511 ? 1022 - row : row) << 9;
    #pragma unroll
    for (int p = 0; p < 6; ++p) {
        const float* g = pb[p] + rb;
        R[p][0] = g[cm1]; R[p][1] = g[c]; R[p][2] = g[cp1]; R[p][3] = g[cp2];
    }
}

// masks of X_'s row at window cols 0..2 (= c-1, c, c+1), using Y_ = row below
__device__ __forceinline__ void mask3(float M[3], const float X_[6][4], const float Y_[6][4])
{
    #pragma unroll
    for (int j = 0; j < 3; ++j) {
        float eo = 0.f, es = 0.f;
        #pragma unroll
        for (int p = 0; p < 3; ++p) {
            float a = X_[p][j];
            float d1 = a - Y_[p][j], d2 = a - X_[p][j + 1];
            eo += d1 * d1 + d2 * d2;
            float s = X_[p + 3][j];
            float f1 = s - Y_[p + 3][j], f2 = s - X_[p + 3][j + 1];
            es += f1 * f1 + f2 * f2;
        }
        M[j] = (eo < 1.f && es - eo > 1.f) ? 1.f : 0.f;
    }
}

// combine partials with masks (+ reflection multiplicities on border waves)
__device__ __forceinline__ float combine(
    const PairP& pE, const PairP& pS, const PairP& pSE, const PairP& pSW,
    float mi, float mE, float mS, float mSE, float mSW,
    int h, int w, bool border)
{
    float a = fmaf(mi, 3e-16f - 1.1943215e-6f, 1.1943215e-6f);  // center offset
    if (!border) {
        a += (2.f - mi - mE ) * pE.ps  + (mi + mE ) * pE.sq;
        a += (2.f - mi - mS ) * pS.ps  + (mi + mS ) * pS.sq;
        a += (2.f - mi - mSE) * pSE.ps + (mi + mSE) * pSE.sq;
        a += (2.f - mi - mSW) * pSW.ps + (mi + mSW) * pSW.sq;
    } else {
        float aE = (w == 0)   ? 2.f : 1.f, bE = (w == 510) ? 2.f : 1.f;
        float aS = (h == 0)   ? 2.f : 1.f, bS = (h == 510) ? 2.f : 1.f;
        float aW = (w == 511) ? 2.f : 1.f, bW = (w == 1)   ? 2.f : 1.f;
        bool  vE = (w <= 510), vS = (h <= 510);
        bool  vD = vS && vE,   vW = vS && (w >= 1);
        float cEf = vE ? aE : 0.f,      cEb = vE ? bE : 0.f;
        float cSf = vS ? aS : 0.f,      cSb = vS ? bS : 0.f;
        float cDf = vD ? aS * aE : 0.f, cDb = vD ? bS * bE : 0.f;
        float cWf = vW ? aS * aW : 0.f, cWb = vW ? bS * bW : 0.f;
        a += (fmaf(cEf, -mi, cEf) + fmaf(cEb, -mE,  cEb)) * pE.ps  + fmaf(cEf, mi, cEb * mE ) * pE.sq;
        a += (fmaf(cSf, -mi, cSf) + fmaf(cSb, -mS,  cSb)) * pS.ps  + fmaf(cSf, mi, cSb * mS ) * pS.sq;
        a += (fmaf(cDf, -mi, cDf) + fmaf(cDb, -mSE, cDb)) * pSE.ps + fmaf(cDf, mi, cDb * mSE) * pSE.sq;
        a += (fmaf(cWf, -mi, cWf) + fmaf(cWb, -mSW, cWb)) * pSW.ps + fmaf(cWf, mi, cWb * mSW) * pSW.sq;
    }
    return a;
}

// one march step: pixel row h0+S uses B_(row h0+S), C_(row h0+S+1);
// N_ receives row h0+S+2 (issued first, consumed last by mask3)
#define MSTEP(B_, C_, N_, S_)                                                   \
    {                                                                           \
        load_row(N_, pb, h0 + (S_) + 2, cm1, c, cp1, cp2);                      \
        PairP pE  = pp<1, 2>(B_, B_, WS1);                                      \
        PairP pS  = pp<1, 1>(B_, C_, WS1);                                      \
        PairP pSE = pp<1, 2>(B_, C_, WS2);                                      \
        PairP pSW = pp<1, 0>(B_, C_, WS2);                                      \
        float mN[3]; mask3(mN, C_, N_);                                         \
        acc += combine(pE, pS, pSE, pSW, mB[1], mB[2], mN[1], mN[2], mN[0],     \
                       h0 + (S_), c, wborder);                                  \
        mB[0] = mN[0]; mB[1] = mN[1]; mB[2] = mN[2];                            \
    }

__global__ __launch_bounds__(256) void smooth_loss_kernel(
    const float* __restrict__ orig, const float* __restrict__ smo,
    float* __restrict__ out)
{
    const int tid  = threadIdx.x;
    const int bid  = blockIdx.x;        // 8 imgs * 64 bands * 2 col-halves
    const int b    = bid >> 7;
    const int rem  = bid & 127;
    const int band = rem >> 1;
    const int half = rem & 1;
    const int h0   = band << 3;         // 8-row segment
    const int c    = (half << 8) | tid; // own column

    // pre-reflected window col indices (c-1, c, c+1, c+2)
    const int cm1 = (c == 0)   ? 1   : c - 1;
    const int cp1 = (c == 511) ? 510 : c + 1;
    const int cp2 = (c >= 510) ? 1022 - (c + 2) : c + 2;

    const int wc = (half << 8) | (tid & 192);   // wave's first col
    const bool wborder = (band == 0) | (band == 63) | (wc == 0) | (wc == 448);

    const float* pb[6];
    #pragma unroll
    for (int p = 0; p < 3; ++p) {
        pb[p]     = orig + ((b * 3 + p) << 18);
        pb[p + 3] = smo  + ((b * 3 + p) << 18);
    }

    float D0[6][4], D1[6][4], D2[6][4];
    float mB[3];
    float acc = 0.f;

    load_row(D0, pb, h0,     cm1, c, cp1, cp2);
    load_row(D1, pb, h0 + 1, cm1, c, cp1, cp2);
    mask3(mB, D0, D1);                  // masks of row h0

    MSTEP(D0, D1, D2, 0)
    MSTEP(D1, D2, D0, 1)
    MSTEP(D2, D0, D1, 2)
    MSTEP(D0, D1, D2, 3)
    MSTEP(D1, D2, D0, 4)
    MSTEP(D2, D0, D1, 5)
    MSTEP(D0, D1, D2, 6)
    MSTEP(D1, D2, D0, 7)

    acc *= (1.0f / 56623104.0f);        // mean over 8*9*3*512*512

    #pragma unroll
    for (int o = 32; o > 0; o >>= 1)
        acc += __shfl_down(acc, o, 64);

    __shared__ float wsum[4];
    const int lane = tid & 63;
    const int wid  = tid >> 6;
    if (lane == 0) wsum[wid] = acc;
    __syncthreads();
    if (tid == 0)
        atomicAdd(out, wsum[0] + wsum[1] + wsum[2] + wsum[3]);
}

extern "C" void kernel_launch(void* const* d_in, const int* in_sizes, int n_in,
                              void* d_out, int out_size, void* d_ws, size_t ws_size,
                              hipStream_t stream) {
    const float* orig = (const float*)d_in[0];
    const float* smo  = (const float*)d_in[1];
    float* out = (float*)d_out;

    (void)hipMemsetAsync(out, 0, sizeof(float), stream);
    smooth_loss_kernel<<<1024, 256, 0, stream>>>(orig, smo, out);
}

// Round 13
// 33.300 us; speedup vs baseline: 2.7388x; 1.0128x over previous
//
#include <hip/hip_runtime.h>

__device__ __forceinline__ float fexp2(float x) { return __builtin_amdgcn_exp2f(x); }
__device__ __forceinline__ float flog2(float x) { return __builtin_amdgcn_logf(x); }

#define WS1 0.60653065971263342f   // exp(-0.5)
#define WS2 0.36787944117144233f   // exp(-1)

struct PairP { float ps, sq; };    // ps = wr*sum(t^0.8) ; sq = wsd*sum(t^2)

// mask-independent pair partials between I[.][CI] and J[.][CJ]  (5-col windows)
template<int CI, int CJ>
__device__ __forceinline__ PairP pp(const float (&I)[6][5], const float (&J)[6][5], float wsd)
{
    float d0 = I[0][CI] - J[0][CJ], d1 = I[1][CI] - J[1][CJ], d2 = I[2][CI] - J[2][CJ];
    float sO = fmaf(d0, d0, fmaf(d1, d1, d2 * d2));
    float t0 = fabsf(I[3][CI] - J[3][CJ]) + 1e-8f;
    float t1 = fabsf(I[4][CI] - J[4][CJ]) + 1e-8f;
    float t2 = fabsf(I[5][CI] - J[5][CJ]) + 1e-8f;
    PairP r;
    r.ps = fexp2(-0.72134752044448169f * sO) *
           (fexp2(0.8f * flog2(t0)) + fexp2(0.8f * flog2(t1)) + fexp2(0.8f * flog2(t2)));
    r.sq = wsd * fmaf(t0, t0, fmaf(t1, t1, t2 * t2));
    return r;
}

// load one image row: 5-col window {cm1, c0, c0+1, cp2, cp3} x 6 planes, 3 instrs/plane
__device__ __forceinline__ void load_row(float R[6][5], const float* const pb[6],
                                         int row, int cm1, int c0, int c2c)
{
    const int rb = (row > 511 ? 1022 - row : row) << 9;
    #pragma unroll
    for (int p = 0; p < 6; ++p) {
        const float* g = pb[p] + rb;
        R[p][0] = g[cm1];
        float2 v0 = *(const float2*)(g + c0);
        R[p][1] = v0.x; R[p][2] = v0.y;
        float2 v2 = *(const float2*)(g + c2c);
        R[p][3] = v2.x; R[p][4] = v2.y;
    }
}

// masks of X_'s row at window cols 0..3 (= c0-1..c0+2), Y_ = row below
__device__ __forceinline__ void mask4(float M[4], const float X_[6][5], const float Y_[6][5])
{
    #pragma unroll
    for (int j = 0; j < 4; ++j) {
        float eo = 0.f, es = 0.f;
        #pragma unroll
        for (int p = 0; p < 3; ++p) {
            float a = X_[p][j];
            float d1 = a - Y_[p][j], d2 = a - X_[p][j + 1];
            eo += d1 * d1 + d2 * d2;
            float s = X_[p + 3][j];
            float f1 = s - Y_[p + 3][j], f2 = s - X_[p + 3][j + 1];
            es += f1 * f1 + f2 * f2;
        }
        M[j] = (eo < 1.f && es - eo > 1.f) ? 1.f : 0.f;
    }
}

// combine partials with masks (+ reflection multiplicities on border waves)
__device__ __forceinline__ float combine(
    const PairP& pE, const PairP& pS, const PairP& pSE, const PairP& pSW,
    float mi, float mE, float mS, float mSE, float mSW,
    int h, int w, bool border)
{
    float a = fmaf(mi, 3e-16f - 1.1943215e-6f, 1.1943215e-6f);  // center offset
    if (!border) {
        a += (2.f - mi - mE ) * pE.ps  + (mi + mE ) * pE.sq;
        a += (2.f - mi - mS ) * pS.ps  + (mi + mS ) * pS.sq;
        a += (2.f - mi - mSE) * pSE.ps + (mi + mSE) * pSE.sq;
        a += (2.f - mi - mSW) * pSW.ps + (mi + mSW) * pSW.sq;
    } else {
        float aE = (w == 0)   ? 2.f : 1.f, bE = (w == 510) ? 2.f : 1.f;
        float aS = (h == 0)   ? 2.f : 1.f, bS = (h == 510) ? 2.f : 1.f;
        float aW = (w == 511) ? 2.f : 1.f, bW = (w == 1)   ? 2.f : 1.f;
        bool  vE = (w <= 510), vS = (h <= 510);
        bool  vD = vS && vE,   vW = vS && (w >= 1);
        float cEf = vE ? aE : 0.f,      cEb = vE ? bE : 0.f;
        float cSf = vS ? aS : 0.f,      cSb = vS ? bS : 0.f;
        float cDf = vD ? aS * aE : 0.f, cDb = vD ? bS * bE : 0.f;
        float cWf = vW ? aS * aW : 0.f, cWb = vW ? bS * bW : 0.f;
        a += (fmaf(cEf, -mi, cEf) + fmaf(cEb, -mE,  cEb)) * pE.ps  + fmaf(cEf, mi, cEb * mE ) * pE.sq;
        a += (fmaf(cSf, -mi, cSf) + fmaf(cSb, -mS,  cSb)) * pS.ps  + fmaf(cSf, mi, cSb * mS ) * pS.sq;
        a += (fmaf(cDf, -mi, cDf) + fmaf(cDb, -mSE, cDb)) * pSE.ps + fmaf(cDf, mi, cDb * mSE) * pSE.sq;
        a += (fmaf(cWf, -mi, cWf) + fmaf(cWb, -mSW, cWb)) * pSW.ps + fmaf(cWf, mi, cWb * mSW) * pSW.sq;
    }
    return a;
}

// one march step: pixel row h0+S (2 px: c0, c0+1) from B_(row h0+S), C_(+1);
// N_ receives row h0+S+2 (issued first, consumed last by mask4)
#define MSTEP(B_, C_, N_, S_)                                                   \
    {                                                                           \
        load_row(N_, pb, h0 + (S_) + 2, cm1, c0, c2c);                          \
        PairP pE0  = pp<1, 2>(B_, B_, WS1);                                     \
        PairP pE1  = pp<2, 3>(B_, B_, WS1);                                     \
        PairP pS0  = pp<1, 1>(B_, C_, WS1);                                     \
        PairP pS1  = pp<2, 2>(B_, C_, WS1);                                     \
        PairP pSE0 = pp<1, 2>(B_, C_, WS2);                                     \
        PairP pSE1 = pp<2, 3>(B_, C_, WS2);                                     \
        PairP pSW0 = pp<1, 0>(B_, C_, WS2);                                     \
        PairP pSW1 = pp<2, 1>(B_, C_, WS2);                                     \
        float mN[4]; mask4(mN, C_, N_);                                         \
        acc += combine(pE0, pS0, pSE0, pSW0, mB[1], mB[2], mN[1], mN[2], mN[0], \
                       h0 + (S_), c0, wborder);                                 \
        acc += combine(pE1, pS1, pSE1, pSW1, mB[2], mB[3], mN[2], mN[3], mN[1], \
                       h0 + (S_), c0 + 1, wborder);                             \
        mB[0] = mN[0]; mB[1] = mN[1]; mB[2] = mN[2]; mB[3] = mN[3];             \
    }

__global__ __launch_bounds__(256) void smooth_loss_kernel(
    const float* __restrict__ orig, const float* __restrict__ smo,
    float* __restrict__ out)
{
    const int tid  = threadIdx.x;
    const int bid  = blockIdx.x;        // 8 imgs * 128 bands (4 rows each)
    const int b    = bid >> 7;
    const int band = bid & 127;
    const int h0   = band << 2;         // 4-row segment
    const int c0   = tid << 1;          // own cols c0, c0+1

    // clamped window col indices; clamped slots are provably zero-weight
    const int cm1 = (c0 == 0) ? 0 : c0 - 1;
    const int c2c = (c0 + 2 > 510) ? 510 : c0 + 2;   // float2 covers cols c2c, c2c+1

    const int wc = (tid & 192) << 1;    // wave's first col (0,128,256,384)
    const bool wborder = (band == 0) | (band == 127) | (wc == 0) | (wc == 384);

    const float* pb[6];
    #pragma unroll
    for (int p = 0; p < 3; ++p) {
        pb[p]     = orig + ((b * 3 + p) << 18);
        pb[p + 3] = smo  + ((b * 3 + p) << 18);
    }

    float D0[6][5], D1[6][5], D2[6][5];
    float mB[4];
    float acc = 0.f;

    load_row(D0, pb, h0,     cm1, c0, c2c);
    load_row(D1, pb, h0 + 1, cm1, c0, c2c);
    mask4(mB, D0, D1);                  // masks of row h0

    MSTEP(D0, D1, D2, 0)
    MSTEP(D1, D2, D0, 1)
    MSTEP(D2, D0, D1, 2)
    MSTEP(D0, D1, D2, 3)

    acc *= (1.0f / 56623104.0f);        // mean over 8*9*3*512*512

    #pragma unroll
    for (int o = 32; o > 0; o >>= 1)
        acc += __shfl_down(acc, o, 64);

    __shared__ float wsum[4];
    const int lane = tid & 63;
    const int wid  = tid >> 6;
    if (lane == 0) wsum[wid] = acc;
    __syncthreads();
    if (tid == 0)
        atomicAdd(out, wsum[0] + wsum[1] + wsum[2] + wsum[3]);
}

extern "C" void kernel_launch(void* const* d_in, const int* in_sizes, int n_in,
                              void* d_out, int out_size, void* d_ws, size_t ws_size,
                              hipStream_t stream) {
    const float* orig = (const float*)d_in[0];
    const float* smo  = (const float*)d_in[1];
    float* out = (float*)d_out;

    (void)hipMemsetAsync(out, 0, sizeof(float), stream);
    smooth_loss_kernel<<<1024, 256, 0, stream>>>(orig, smo, out);
}

// Round 14
// 32.744 us; speedup vs baseline: 2.7853x; 1.0170x over previous
//
#include <hip/hip_runtime.h>

__device__ __forceinline__ float fexp2(float x) { return __builtin_amdgcn_exp2f(x); }
__device__ __forceinline__ float flog2(float x) { return __builtin_amdgcn_logf(x); }

#define WS1 0.60653065971263342f   // exp(-0.5)
#define WS2 0.36787944117144233f   // exp(-1)

struct PairP { float ps, sq; };    // ps = wr*sum(t^0.8) ; sq = wsd*sum(t^2)

// mask-independent pair partials between I[.][CI] and J[.][CJ]
template<int CI, int CJ>
__device__ __forceinline__ PairP pp(const float (&I)[6][4], const float (&J)[6][4], float wsd)
{
    float d0 = I[0][CI] - J[0][CJ], d1 = I[1][CI] - J[1][CJ], d2 = I[2][CI] - J[2][CJ];
    float sO = fmaf(d0, d0, fmaf(d1, d1, d2 * d2));
    float t0 = fabsf(I[3][CI] - J[3][CJ]) + 1e-8f;
    float t1 = fabsf(I[4][CI] - J[4][CJ]) + 1e-8f;
    float t2 = fabsf(I[5][CI] - J[5][CJ]) + 1e-8f;
    PairP r;
    r.ps = fexp2(-0.72134752044448169f * sO) *
           (fexp2(0.8f * flog2(t0)) + fexp2(0.8f * flog2(t1)) + fexp2(0.8f * flog2(t2)));
    r.sq = wsd * fmaf(t0, t0, fmaf(t1, t1, t2 * t2));
    return r;
}

// load one image row: 4-col window (cm1, c, cp1, cp2 pre-reflected) x 6 planes
__device__ __forceinline__ void load_row(float R[6][4], const float* const pb[6],
                                         int row, int cm1, int c, int cp1, int cp2)
{
    const int rb = (row > 511 ? 1022 - row : row) << 9;
    #pragma unroll
    for (int p = 0; p < 6; ++p) {
        const float* g = pb[p] + rb;
        R[p][0] = g[cm1]; R[p][1] = g[c]; R[p][2] = g[cp1]; R[p][3] = g[cp2];
    }
}

// masks of X_'s row at window cols 0..2 (= c-1, c, c+1), using Y_ = row below
__device__ __forceinline__ void mask3(float M[3], const float X_[6][4], const float Y_[6][4])
{
    #pragma unroll
    for (int j = 0; j < 3; ++j) {
        float eo = 0.f, es = 0.f;
        #pragma unroll
        for (int p = 0; p < 3; ++p) {
            float a = X_[p][j];
            float d1 = a - Y_[p][j], d2 = a - X_[p][j + 1];
            eo += d1 * d1 + d2 * d2;
            float s = X_[p + 3][j];
            float f1 = s - Y_[p + 3][j], f2 = s - X_[p + 3][j + 1];
            es += f1 * f1 + f2 * f2;
        }
        M[j] = (eo < 1.f && es - eo > 1.f) ? 1.f : 0.f;
    }
}

// combine partials with masks (+ reflection multiplicities on border waves)
__device__ __forceinline__ float combine(
    const PairP& pE, const PairP& pS, const PairP& pSE, const PairP& pSW,
    float mi, float mE, float mS, float mSE, float mSW,
    int h, int w, bool border)
{
    float a = fmaf(mi, 3e-16f - 1.1943215e-6f, 1.1943215e-6f);  // center offset
    if (!border) {
        a += (2.f - mi - mE ) * pE.ps  + (mi + mE ) * pE.sq;
        a += (2.f - mi - mS ) * pS.ps  + (mi + mS ) * pS.sq;
        a += (2.f - mi - mSE) * pSE.ps + (mi + mSE) * pSE.sq;
        a += (2.f - mi - mSW) * pSW.ps + (mi + mSW) * pSW.sq;
    } else {
        float aE = (w == 0)   ? 2.f : 1.f, bE = (w == 510) ? 2.f : 1.f;
        float aS = (h == 0)   ? 2.f : 1.f, bS = (h == 510) ? 2.f : 1.f;
        float aW = (w == 511) ? 2.f : 1.f, bW = (w == 1)   ? 2.f : 1.f;
        bool  vE = (w <= 510), vS = (h <= 510);
        bool  vD = vS && vE,   vW = vS && (w >= 1);
        float cEf = vE ? aE : 0.f,      cEb = vE ? bE : 0.f;
        float cSf = vS ? aS : 0.f,      cSb = vS ? bS : 0.f;
        float cDf = vD ? aS * aE : 0.f, cDb = vD ? bS * bE : 0.f;
        float cWf = vW ? aS * aW : 0.f, cWb = vW ? bS * bW : 0.f;
        a += (fmaf(cEf, -mi, cEf) + fmaf(cEb, -mE,  cEb)) * pE.ps  + fmaf(cEf, mi, cEb * mE ) * pE.sq;
        a += (fmaf(cSf, -mi, cSf) + fmaf(cSb, -mS,  cSb)) * pS.ps  + fmaf(cSf, mi, cSb * mS ) * pS.sq;
        a += (fmaf(cDf, -mi, cDf) + fmaf(cDb, -mSE, cDb)) * pSE.ps + fmaf(cDf, mi, cDb * mSE) * pSE.sq;
        a += (fmaf(cWf, -mi, cWf) + fmaf(cWb, -mSW, cWb)) * pSW.ps + fmaf(cWf, mi, cWb * mSW) * pSW.sq;
    }
    return a;
}

// depth-2 march step for pixel row h0+S:
//   B_ = row h0+S, C_ = row h0+S+1, N1_ = row h0+S+2 (loaded LAST step),
//   NL_ receives row h0+S+3 (issued now, consumed NEXT step by mask3)
#define MSTEP(B_, C_, N1_, NL_, S_, DOLOAD_)                                    \
    {                                                                           \
        if (DOLOAD_) load_row(NL_, pb, h0 + (S_) + 3, cm1, c, cp1, cp2);        \
        PairP pE  = pp<1, 2>(B_, B_, WS1);                                      \
        PairP pS  = pp<1, 1>(B_, C_, WS1);                                      \
        PairP pSE = pp<1, 2>(B_, C_, WS2);                                      \
        PairP pSW = pp<1, 0>(B_, C_, WS2);                                      \
        float mN[3]; mask3(mN, C_, N1_);                                        \
        acc += combine(pE, pS, pSE, pSW, mB[1], mB[2], mN[1], mN[2], mN[0],     \
                       h0 + (S_), c, wborder);                                  \
        mB[0] = mN[0]; mB[1] = mN[1]; mB[2] = mN[2];                            \
    }

__global__ __launch_bounds__(256) void smooth_loss_kernel(
    const float* __restrict__ orig, const float* __restrict__ smo,
    float* __restrict__ out)
{
    const int tid  = threadIdx.x;
    const int bid  = blockIdx.x;        // 8 imgs * 64 bands * 2 col-halves
    const int b    = bid >> 7;
    const int rem  = bid & 127;
    const int band = rem >> 1;
    const int half = rem & 1;
    const int h0   = band << 3;         // 8-row segment
    const int c    = (half << 8) | tid; // own column

    // pre-reflected window col indices (c-1, c, c+1, c+2)
    const int cm1 = (c == 0)   ? 1   : c - 1;
    const int cp1 = (c == 511) ? 510 : c + 1;
    const int cp2 = (c >= 510) ? 1022 - (c + 2) : c + 2;

    const int wc = (half << 8) | (tid & 192);   // wave's first col
    const bool wborder = (band == 0) | (band == 63) | (wc == 0) | (wc == 448);

    const float* pb[6];
    #pragma unroll
    for (int p = 0; p < 3; ++p) {
        pb[p]     = orig + ((b * 3 + p) << 18);
        pb[p + 3] = smo  + ((b * 3 + p) << 18);
    }

    float D0[6][4], D1[6][4], D2[6][4], D3[6][4];
    float mB[3];
    float acc = 0.f;

    // prologue: rows h0 .. h0+2 in flight, mask of row h0
    load_row(D0, pb, h0,     cm1, c, cp1, cp2);
    load_row(D1, pb, h0 + 1, cm1, c, cp1, cp2);
    load_row(D2, pb, h0 + 2, cm1, c, cp1, cp2);
    mask3(mB, D0, D1);

    //       B   C   N1  NL   S  load?
    MSTEP(D0, D1, D2, D3, 0, 1)        // loads h0+3
    MSTEP(D1, D2, D3, D0, 1, 1)        // loads h0+4
    MSTEP(D2, D3, D0, D1, 2, 1)        // loads h0+5
    MSTEP(D3, D0, D1, D2, 3, 1)        // loads h0+6
    MSTEP(D0, D1, D2, D3, 4, 1)        // loads h0+7
    MSTEP(D1, D2, D3, D0, 5, 1)        // loads h0+8
    MSTEP(D2, D3, D0, D1, 6, 1)        // loads h0+9
    MSTEP(D3, D0, D1, D2, 7, 0)        // consumes h0+8 (B), h0+9 (N1)

    acc *= (1.0f / 56623104.0f);        // mean over 8*9*3*512*512

    #pragma unroll
    for (int o = 32; o > 0; o >>= 1)
        acc += __shfl_down(acc, o, 64);

    __shared__ float wsum[4];
    const int lane = tid & 63;
    const int wid  = tid >> 6;
    if (lane == 0) wsum[wid] = acc;
    __syncthreads();
    if (tid == 0)
        atomicAdd(out, wsum[0] + wsum[1] + wsum[2] + wsum[3]);
}

extern "C" void kernel_launch(void* const* d_in, const int* in_sizes, int n_in,
                              void* d_out, int out_size, void* d_ws, size_t ws_size,
                              hipStream_t stream) {
    const float* orig = (const float*)d_in[0];
    const float* smo  = (const float*)d_in[1];
    float* out = (float*)d_out;

    (void)hipMemsetAsync(out, 0, sizeof(float), stream);
    smooth_loss_kernel<<<1024, 256, 0, stream>>>(orig, smo, out);
}

// Round 15
// 31.553 us; speedup vs baseline: 2.8905x; 1.0378x over previous
//
#include <hip/hip_runtime.h>

__device__ __forceinline__ float fexp2(float x) { return __builtin_amdgcn_exp2f(x); }
__device__ __forceinline__ float flog2(float x) { return __builtin_amdgcn_logf(x); }

#define WS1 0.60653065971263342f   // exp(-0.5)
#define WS2 0.36787944117144233f   // exp(-1)

struct PairP { float ps, sq; };    // ps = wr*sum(t^0.8) ; sq = wsd*sum(t^2)

// mask-independent pair partials between I[.][CI] and J[.][CJ]
template<int CI, int CJ>
__device__ __forceinline__ PairP pp(const float (&I)[6][4], const float (&J)[6][4], float wsd)
{
    float d0 = I[0][CI] - J[0][CJ], d1 = I[1][CI] - J[1][CJ], d2 = I[2][CI] - J[2][CJ];
    float sO = fmaf(d0, d0, fmaf(d1, d1, d2 * d2));
    float t0 = fabsf(I[3][CI] - J[3][CJ]) + 1e-8f;
    float t1 = fabsf(I[4][CI] - J[4][CJ]) + 1e-8f;
    float t2 = fabsf(I[5][CI] - J[5][CJ]) + 1e-8f;
    PairP r;
    r.ps = fexp2(-0.72134752044448169f * sO) *
           (fexp2(0.8f * flog2(t0)) + fexp2(0.8f * flog2(t1)) + fexp2(0.8f * flog2(t2)));
    r.sq = wsd * fmaf(t0, t0, fmaf(t1, t1, t2 * t2));
    return r;
}

// load one image row: 4-col window (cm1, c, cp1, cp2 pre-reflected) x 6 planes
__device__ __forceinline__ void load_row(float R[6][4], const float* const pb[6],
                                         int row, int cm1, int c, int cp1, int cp2)
{
    const int rb = (row > 511 ? 1022 - row : row) << 9;
    #pragma unroll
    for (int p = 0; p < 6; ++p) {
        const float* g = pb[p] + rb;
        R[p][0] = g[cm1]; R[p][1] = g[c]; R[p][2] = g[cp1]; R[p][3] = g[cp2];
    }
}

// masks of X_'s row at window cols 0..2 (= c-1, c, c+1), using Y_ = row below
__device__ __forceinline__ void mask3(float M[3], const float X_[6][4], const float Y_[6][4])
{
    #pragma unroll
    for (int j = 0; j < 3; ++j) {
        float eo = 0.f, es = 0.f;
        #pragma unroll
        for (int p = 0; p < 3; ++p) {
            float a = X_[p][j];
            float d1 = a - Y_[p][j], d2 = a - X_[p][j + 1];
            eo += d1 * d1 + d2 * d2;
            float s = X_[p + 3][j];
            float f1 = s - Y_[p + 3][j], f2 = s - X_[p + 3][j + 1];
            es += f1 * f1 + f2 * f2;
        }
        M[j] = (eo < 1.f && es - eo > 1.f) ? 1.f : 0.f;
    }
}

// combine partials with masks (+ reflection multiplicities on border waves)
__device__ __forceinline__ float combine(
    const PairP& pE, const PairP& pS, const PairP& pSE, const PairP& pSW,
    float mi, float mE, float mS, float mSE, float mSW,
    int h, int w, bool border)
{
    float a = fmaf(mi, 3e-16f - 1.1943215e-6f, 1.1943215e-6f);  // center offset
    if (!border) {
        a += (2.f - mi - mE ) * pE.ps  + (mi + mE ) * pE.sq;
        a += (2.f - mi - mS ) * pS.ps  + (mi + mS ) * pS.sq;
        a += (2.f - mi - mSE) * pSE.ps + (mi + mSE) * pSE.sq;
        a += (2.f - mi - mSW) * pSW.ps + (mi + mSW) * pSW.sq;
    } else {
        float aE = (w == 0)   ? 2.f : 1.f, bE = (w == 510) ? 2.f : 1.f;
        float aS = (h == 0)   ? 2.f : 1.f, bS = (h == 510) ? 2.f : 1.f;
        float aW = (w == 511) ? 2.f : 1.f, bW = (w == 1)   ? 2.f : 1.f;
        bool  vE = (w <= 510), vS = (h <= 510);
        bool  vD = vS && vE,   vW = vS && (w >= 1);
        float cEf = vE ? aE : 0.f,      cEb = vE ? bE : 0.f;
        float cSf = vS ? aS : 0.f,      cSb = vS ? bS : 0.f;
        float cDf = vD ? aS * aE : 0.f, cDb = vD ? bS * bE : 0.f;
        float cWf = vW ? aS * aW : 0.f, cWb = vW ? bS * bW : 0.f;
        a += (fmaf(cEf, -mi, cEf) + fmaf(cEb, -mE,  cEb)) * pE.ps  + fmaf(cEf, mi, cEb * mE ) * pE.sq;
        a += (fmaf(cSf, -mi, cSf) + fmaf(cSb, -mS,  cSb)) * pS.ps  + fmaf(cSf, mi, cSb * mS ) * pS.sq;
        a += (fmaf(cDf, -mi, cDf) + fmaf(cDb, -mSE, cDb)) * pSE.ps + fmaf(cDf, mi, cDb * mSE) * pSE.sq;
        a += (fmaf(cWf, -mi, cWf) + fmaf(cWb, -mSW, cWb)) * pSW.ps + fmaf(cWf, mi, cWb * mSW) * pSW.sq;
    }
    return a;
}

// march step for pixel row h0+S: B_=row h0+S, C_=+1, N1_=+2 (loaded last step),
// NL_ receives row h0+S+3 (issued now, consumed next step by mask3)
#define MSTEP(B_, C_, N1_, NL_, S_)                                             \
    {                                                                           \
        load_row(NL_, pb, h0 + (S_) + 3, cm1, c, cp1, cp2);                     \
        PairP pE  = pp<1, 2>(B_, B_, WS1);                                      \
        PairP pS  = pp<1, 1>(B_, C_, WS1);                                      \
        PairP pSE = pp<1, 2>(B_, C_, WS2);                                      \
        PairP pSW = pp<1, 0>(B_, C_, WS2);                                      \
        float mN[3]; mask3(mN, C_, N1_);                                        \
        acc += combine(pE, pS, pSE, pSW, mB[1], mB[2], mN[1], mN[2], mN[0],     \
                       h0 + (S_), c, wborder);                                  \
        mB[0] = mN[0]; mB[1] = mN[1]; mB[2] = mN[2];                            \
    }

__global__ __launch_bounds__(256) void smooth_loss_kernel(
    const float* __restrict__ orig, const float* __restrict__ smo,
    float* __restrict__ out)
{
    const int tid  = threadIdx.x;
    const int bid  = blockIdx.x;        // 8 imgs * 32 bands * 2 col-halves
    const int b    = bid >> 6;
    const int rem  = bid & 63;
    const int band = rem >> 1;
    const int half = rem & 1;
    const int h0   = band << 4;         // 16-row segment
    const int c    = (half << 8) | tid; // own column

    // pre-reflected window col indices (c-1, c, c+1, c+2)
    const int cm1 = (c == 0)   ? 1   : c - 1;
    const int cp1 = (c == 511) ? 510 : c + 1;
    const int cp2 = (c >= 510) ? 1022 - (c + 2) : c + 2;

    const int wc = (half << 8) | (tid & 192);   // wave's first col
    const bool wborder = (band == 0) | (band == 31) | (wc == 0) | (wc == 448);

    const float* pb[6];
    #pragma unroll
    for (int p = 0; p < 3; ++p) {
        pb[p]     = orig + ((b * 3 + p) << 18);
        pb[p + 3] = smo  + ((b * 3 + p) << 18);
    }

    float D0[6][4], D1[6][4], D2[6][4], D3[6][4];
    float mB[3];
    float acc = 0.f;

    // prologue: rows h0 .. h0+2 in flight, mask of row h0
    load_row(D0, pb, h0,     cm1, c, cp1, cp2);
    load_row(D1, pb, h0 + 1, cm1, c, cp1, cp2);
    load_row(D2, pb, h0 + 2, cm1, c, cp1, cp2);
    mask3(mB, D0, D1);

    // rolled march: 4 iterations x 4 steps; buffer rotation period == body length.
    // Final step's prefetch (row h0+18 <= 514, reflected to <=508) is dead but safe.
    #pragma unroll 1
    for (int g = 0; g < 4; ++g) {
        const int s0 = g << 2;
        MSTEP(D0, D1, D2, D3, s0 + 0)
        MSTEP(D1, D2, D3, D0, s0 + 1)
        MSTEP(D2, D3, D0, D1, s0 + 2)
        MSTEP(D3, D0, D1, D2, s0 + 3)
    }

    acc *= (1.0f / 56623104.0f);        // mean over 8*9*3*512*512

    #pragma unroll
    for (int o = 32; o > 0; o >>= 1)
        acc += __shfl_down(acc, o, 64);

    __shared__ float wsum[4];
    const int lane = tid & 63;
    const int wid  = tid >> 6;
    if (lane == 0) wsum[wid] = acc;
    __syncthreads();
    if (tid == 0)
        atomicAdd(out, wsum[0] + wsum[1] + wsum[2] + wsum[3]);
}

extern "C" void kernel_launch(void* const* d_in, const int* in_sizes, int n_in,
                              void* d_out, int out_size, void* d_ws, size_t ws_size,
                              hipStream_t stream) {
    const float* orig = (const float*)d_in[0];
    const float* smo  = (const float*)d_in[1];
    float* out = (float*)d_out;

    (void)hipMemsetAsync(out, 0, sizeof(float), stream);
    smooth_loss_kernel<<<512, 256, 0, stream>>>(orig, smo, out);
}